// Round 1
// baseline (724.587 us; speedup 1.0000x reference)
//
#include <hip/hip_runtime.h>
#include <hip/hip_bf16.h>

// Problem: LossVariance — B=16, C=32, H=W=512, L=64 labels.
// loss = mean_b [ sum_{l!=0} var_sum(b,l) / (num_unique_b + 1e-8) ]
// var_sum(b,l) = (q - sum_c s_c^2 / cnt) / (cnt-1)  if cnt>1 else 0
//   where q = sum over pixels in segment of sum_c x^2 (scalar per segment!)

#define LBL 64
#define CH 32
constexpr int PIX  = 512 * 512;   // pixels per batch
constexpr int BATCH = 16;
constexpr int BPB  = 64;          // blocks per batch
constexpr int TPB  = 256;
constexpr int PPB  = PIX / BPB;           // 4096 pixels per block
constexpr int ITERS = PPB / (TPB * 4);    // 4 iterations of float4 groups

// ws layout (floats): s_g[B][C][L] (32768) | q_g[B][L] (1024) | c_g[B][L] (1024)
constexpr int S_G_FLOATS = BATCH * CH * LBL;   // 32768
constexpr int Q_G_OFF    = S_G_FLOATS;         // 32768
constexpr int C_G_OFF    = Q_G_OFF + BATCH * LBL; // 33792
constexpr int WS_FLOATS  = C_G_OFF + BATCH * LBL; // 34816

__global__ __launch_bounds__(TPB) void seg_stats(
    const float* __restrict__ x, const int* __restrict__ tg,
    float* __restrict__ s_g, float* __restrict__ q_g, float* __restrict__ c_g)
{
    __shared__ float s_l[CH][LBL];
    __shared__ float q_l[LBL];
    __shared__ float c_l[LBL];

    const int b   = blockIdx.y;
    const int tid = threadIdx.x;

    for (int i = tid; i < CH * LBL; i += TPB) (&s_l[0][0])[i] = 0.f;
    if (tid < LBL) { q_l[tid] = 0.f; c_l[tid] = 0.f; }
    __syncthreads();

    const float* xb = x  + (size_t)b * CH * PIX;
    const int*   tb = tg + (size_t)b * PIX;
    const int p0 = blockIdx.x * PPB;

    for (int it = 0; it < ITERS; ++it) {
        const int p = p0 + it * (TPB * 4) + tid * 4;
        const int4 lab = *reinterpret_cast<const int4*>(tb + p);
        float q0 = 0.f, q1 = 0.f, q2 = 0.f, q3 = 0.f;
        #pragma unroll 8
        for (int c = 0; c < CH; ++c) {
            const float4 v = *reinterpret_cast<const float4*>(xb + (size_t)c * PIX + p);
            unsafeAtomicAdd(&s_l[c][lab.x], v.x);
            unsafeAtomicAdd(&s_l[c][lab.y], v.y);
            unsafeAtomicAdd(&s_l[c][lab.z], v.z);
            unsafeAtomicAdd(&s_l[c][lab.w], v.w);
            q0 = fmaf(v.x, v.x, q0);
            q1 = fmaf(v.y, v.y, q1);
            q2 = fmaf(v.z, v.z, q2);
            q3 = fmaf(v.w, v.w, q3);
        }
        unsafeAtomicAdd(&q_l[lab.x], q0);
        unsafeAtomicAdd(&q_l[lab.y], q1);
        unsafeAtomicAdd(&q_l[lab.z], q2);
        unsafeAtomicAdd(&q_l[lab.w], q3);
        unsafeAtomicAdd(&c_l[lab.x], 1.f);
        unsafeAtomicAdd(&c_l[lab.y], 1.f);
        unsafeAtomicAdd(&c_l[lab.z], 1.f);
        unsafeAtomicAdd(&c_l[lab.w], 1.f);
    }
    __syncthreads();

    float* sg = s_g + (size_t)b * CH * LBL;
    for (int i = tid; i < CH * LBL; i += TPB)
        unsafeAtomicAdd(&sg[i], (&s_l[0][0])[i]);
    if (tid < LBL) {
        unsafeAtomicAdd(&q_g[b * LBL + tid], q_l[tid]);
        unsafeAtomicAdd(&c_g[b * LBL + tid], c_l[tid]);
    }
}

__global__ __launch_bounds__(1024) void finalize(
    const float* __restrict__ s_g, const float* __restrict__ q_g,
    const float* __restrict__ c_g, float* __restrict__ out)
{
    const int t = threadIdx.x;        // 0..1023
    const int b = t >> 6;             // wave b == batch b (64 lanes per wave)
    const int l = t & 63;

    const float cnt = c_g[b * LBL + l];
    const float q   = q_g[b * LBL + l];
    float sum2 = 0.f;
    const float* sg = s_g + (size_t)b * CH * LBL + l;
    #pragma unroll
    for (int c = 0; c < CH; ++c) {
        const float s = sg[c * LBL];
        sum2 = fmaf(s, s, sum2);
    }

    float var_sum = 0.f;
    if (cnt > 1.f) var_sum = (q - sum2 / cnt) / (cnt - 1.f);

    float v       = (l != 0) ? var_sum : 0.f;
    float present = (l != 0 && cnt > 0.f) ? 1.f : 0.f;

    // reduce across the 64 lanes of this wave (one batch per wave)
    #pragma unroll
    for (int off = 32; off > 0; off >>= 1) {
        v       += __shfl_down(v, off);
        present += __shfl_down(present, off);
    }

    __shared__ float partial[BATCH];
    if (l == 0) partial[b] = v / (present + 1e-8f);
    __syncthreads();
    if (t == 0) {
        float acc = 0.f;
        #pragma unroll
        for (int i = 0; i < BATCH; ++i) acc += partial[i];
        out[0] = acc / (float)BATCH;
    }
}

// Fallback if ws is too small: one block per batch, full batch in LDS.
__global__ __launch_bounds__(1024) void fallback_all(
    const float* __restrict__ x, const int* __restrict__ tg,
    float* __restrict__ out)
{
    __shared__ float s_l[CH][LBL];
    __shared__ float q_l[LBL];
    __shared__ float c_l[LBL];

    const int b   = blockIdx.x;
    const int tid = threadIdx.x;

    for (int i = tid; i < CH * LBL; i += 1024) (&s_l[0][0])[i] = 0.f;
    if (tid < LBL) { q_l[tid] = 0.f; c_l[tid] = 0.f; }
    __syncthreads();

    const float* xb = x  + (size_t)b * CH * PIX;
    const int*   tb = tg + (size_t)b * PIX;

    for (int base = 0; base < PIX; base += 1024 * 4) {
        const int p = base + tid * 4;
        const int4 lab = *reinterpret_cast<const int4*>(tb + p);
        float q0 = 0.f, q1 = 0.f, q2 = 0.f, q3 = 0.f;
        #pragma unroll 8
        for (int c = 0; c < CH; ++c) {
            const float4 v = *reinterpret_cast<const float4*>(xb + (size_t)c * PIX + p);
            unsafeAtomicAdd(&s_l[c][lab.x], v.x);
            unsafeAtomicAdd(&s_l[c][lab.y], v.y);
            unsafeAtomicAdd(&s_l[c][lab.z], v.z);
            unsafeAtomicAdd(&s_l[c][lab.w], v.w);
            q0 = fmaf(v.x, v.x, q0);
            q1 = fmaf(v.y, v.y, q1);
            q2 = fmaf(v.z, v.z, q2);
            q3 = fmaf(v.w, v.w, q3);
        }
        unsafeAtomicAdd(&q_l[lab.x], q0);
        unsafeAtomicAdd(&q_l[lab.y], q1);
        unsafeAtomicAdd(&q_l[lab.z], q2);
        unsafeAtomicAdd(&q_l[lab.w], q3);
        unsafeAtomicAdd(&c_l[lab.x], 1.f);
        unsafeAtomicAdd(&c_l[lab.y], 1.f);
        unsafeAtomicAdd(&c_l[lab.z], 1.f);
        unsafeAtomicAdd(&c_l[lab.w], 1.f);
    }
    __syncthreads();

    if (tid < LBL) {
        const int l = tid;
        const float cnt = c_l[l];
        const float q   = q_l[l];
        float sum2 = 0.f;
        #pragma unroll
        for (int c = 0; c < CH; ++c) sum2 = fmaf(s_l[c][l], s_l[c][l], sum2);
        float var_sum = 0.f;
        if (cnt > 1.f) var_sum = (q - sum2 / cnt) / (cnt - 1.f);
        float v       = (l != 0) ? var_sum : 0.f;
        float present = (l != 0 && cnt > 0.f) ? 1.f : 0.f;
        #pragma unroll
        for (int off = 32; off > 0; off >>= 1) {
            v       += __shfl_down(v, off);
            present += __shfl_down(present, off);
        }
        if (l == 0)
            unsafeAtomicAdd(out, v / (present + 1e-8f) / (float)BATCH);
    }
}

extern "C" void kernel_launch(void* const* d_in, const int* in_sizes, int n_in,
                              void* d_out, int out_size, void* d_ws, size_t ws_size,
                              hipStream_t stream)
{
    const float* x  = (const float*)d_in[0];
    const int*   tg = (const int*)d_in[1];
    float* out = (float*)d_out;
    float* ws  = (float*)d_ws;

    if (ws_size >= WS_FLOATS * sizeof(float)) {
        hipMemsetAsync(d_ws, 0, WS_FLOATS * sizeof(float), stream);
        dim3 grid(BPB, BATCH);
        seg_stats<<<grid, TPB, 0, stream>>>(x, tg, ws, ws + Q_G_OFF, ws + C_G_OFF);
        finalize<<<1, 1024, 0, stream>>>(ws, ws + Q_G_OFF, ws + C_G_OFF, out);
    } else {
        hipMemsetAsync(d_out, 0, sizeof(float), stream);
        fallback_all<<<BATCH, 1024, 0, stream>>>(x, tg, out);
    }
}

// Round 2
// 226.066 us; speedup vs baseline: 3.2052x; 3.2052x over previous
//
#include <hip/hip_runtime.h>
#include <hip/hip_bf16.h>

// LossVariance — B=16, C=32, H=W=512, L=64.
// loss = mean_b [ sum_{l!=0} var_sum(b,l) / (num_unique_b + 1e-8) ]
// var_sum(b,l) = (q - sum_c s_c^2/cnt) / (cnt-1), cnt>1 else 0
//   s[b,l,c] = sum_{p: t=l} x[b,c,p]   (one-hot GEMM on MFMA)
//   q[b,l]   = sum_c ss[b,l,c], ss from MFMA with B = bf16(x*x)
//   cnt      = LDS histogram of labels

#define LBL 64
#define CH 32
constexpr int PIX   = 512 * 512;
constexpr int BATCH = 16;
constexpr int BPB   = 64;                 // blocks per batch
constexpr int TPB   = 256;                // 4 waves
constexpr int PPB   = PIX / BPB;          // 4096 pixels per block
constexpr int WAVE_PIX = PPB / 4;         // 1024 pixels per wave
constexpr int KSTEPS   = WAVE_PIX / 32;   // 32 K-steps of 32 pixels

typedef __attribute__((ext_vector_type(8))) short bf16x8;
typedef __attribute__((ext_vector_type(4))) float f32x4;

// ws layout (floats): s_g[B][L][C] | q_g[B][L] | c_g[B][L]
constexpr int Q_OFF     = BATCH * LBL * CH;        // 32768
constexpr int C_OFF     = Q_OFF + BATCH * LBL;     // 33792
constexpr int WS_FLOATS = C_OFF + BATCH * LBL;     // 34816 (136 KiB)

static __device__ __forceinline__ short f2bf(float f) {
    __hip_bfloat16 h = __float2bfloat16(f);
    return __builtin_bit_cast(short, h);
}
static __device__ __forceinline__ bf16x8 pack8(float4 a, float4 b) {
    bf16x8 r;
    r[0]=f2bf(a.x); r[1]=f2bf(a.y); r[2]=f2bf(a.z); r[3]=f2bf(a.w);
    r[4]=f2bf(b.x); r[5]=f2bf(b.y); r[6]=f2bf(b.z); r[7]=f2bf(b.w);
    return r;
}
static __device__ __forceinline__ float4 sq4(float4 a) {
    return make_float4(a.x*a.x, a.y*a.y, a.z*a.z, a.w*a.w);
}

__global__ __launch_bounds__(TPB) void seg_mfma(
    const float* __restrict__ x, const int* __restrict__ tg,
    float* __restrict__ s_g, float* __restrict__ q_g, float* __restrict__ c_g)
{
    __shared__ float    s_blk[LBL][CH + 1];
    __shared__ float    ss_blk[LBL][CH + 1];
    __shared__ unsigned c_hist[LBL];

    const int b    = blockIdx.y;
    const int tid  = threadIdx.x;
    const int wave = tid >> 6;
    const int lane = tid & 63;
    const int p0   = blockIdx.x * PPB;

    for (int i = tid; i < LBL * (CH + 1); i += TPB) {
        (&s_blk[0][0])[i]  = 0.f;
        (&ss_blk[0][0])[i] = 0.f;
    }
    if (tid < LBL) c_hist[tid] = 0u;
    __syncthreads();

    const float* xb = x  + (size_t)b * CH * PIX;
    const int*   tb = tg + (size_t)b * PIX;

    // ---- label histogram: 16 labels per thread (4M LDS atomics total — cheap)
    {
        const int base = p0 + tid * 16;
        #pragma unroll
        for (int j = 0; j < 4; ++j) {
            const int4 lv = *reinterpret_cast<const int4*>(tb + base + j * 4);
            atomicAdd(&c_hist[lv.x], 1u);
            atomicAdd(&c_hist[lv.y], 1u);
            atomicAdd(&c_hist[lv.z], 1u);
            atomicAdd(&c_hist[lv.w], 1u);
        }
    }

    // ---- one-hot MFMA main loop
    const int kgrp = lane >> 4;      // K sub-block 0..3 (8 pixels each)
    const int lo   = lane & 15;      // A: label-within-tile / B: channel-within-tile
    const int pw   = p0 + wave * WAVE_PIX + kgrp * 8;

    const int*   tA = tb + pw;
    const float* xA = xb + (size_t)lo * PIX + pw;         // channels 0..15
    const float* xB = xA + (size_t)16 * PIX;              // channels 16..31

    f32x4 acc_s[4][2], acc_q[4][2];
    #pragma unroll
    for (int m = 0; m < 4; ++m)
        #pragma unroll
        for (int n = 0; n < 2; ++n) {
            acc_s[m][n] = (f32x4){0.f, 0.f, 0.f, 0.f};
            acc_q[m][n] = (f32x4){0.f, 0.f, 0.f, 0.f};
        }

    for (int ks = 0; ks < KSTEPS; ++ks) {
        const int off = ks * 32;
        const int4   l0 = *reinterpret_cast<const int4*>(tA + off);
        const int4   l1 = *reinterpret_cast<const int4*>(tA + off + 4);
        const float4 u0 = *reinterpret_cast<const float4*>(xA + off);
        const float4 u1 = *reinterpret_cast<const float4*>(xA + off + 4);
        const float4 v0 = *reinterpret_cast<const float4*>(xB + off);
        const float4 v1 = *reinterpret_cast<const float4*>(xB + off + 4);

        const bf16x8 bx0 = pack8(u0, u1);
        const bf16x8 bx1 = pack8(v0, v1);
        const bf16x8 bq0 = pack8(sq4(u0), sq4(u1));
        const bf16x8 bq1 = pack8(sq4(v0), sq4(v1));

        const int labs[8] = {l0.x, l0.y, l0.z, l0.w, l1.x, l1.y, l1.z, l1.w};
        const short ONE = (short)0x3F80;   // bf16 1.0
        bf16x8 am[4];
        #pragma unroll
        for (int m = 0; m < 4; ++m) {
            const int target = lo + m * 16;
            #pragma unroll
            for (int j = 0; j < 8; ++j)
                am[m][j] = (labs[j] == target) ? ONE : (short)0;
        }

        #pragma unroll
        for (int m = 0; m < 4; ++m) {
            acc_s[m][0] = __builtin_amdgcn_mfma_f32_16x16x32_bf16(am[m], bx0, acc_s[m][0], 0, 0, 0);
            acc_s[m][1] = __builtin_amdgcn_mfma_f32_16x16x32_bf16(am[m], bx1, acc_s[m][1], 0, 0, 0);
            acc_q[m][0] = __builtin_amdgcn_mfma_f32_16x16x32_bf16(am[m], bq0, acc_q[m][0], 0, 0, 0);
            acc_q[m][1] = __builtin_amdgcn_mfma_f32_16x16x32_bf16(am[m], bq1, acc_q[m][1], 0, 0, 0);
        }
    }

    // ---- accumulate fragments into block LDS (C/D layout: col=lane&15, row=(lane>>4)*4+r)
    #pragma unroll
    for (int m = 0; m < 4; ++m)
        #pragma unroll
        for (int n = 0; n < 2; ++n)
            #pragma unroll
            for (int r = 0; r < 4; ++r) {
                const int row = m * 16 + kgrp * 4 + r;
                const int col = n * 16 + lo;
                unsafeAtomicAdd(&s_blk[row][col],  acc_s[m][n][r]);
                unsafeAtomicAdd(&ss_blk[row][col], acc_q[m][n][r]);
            }
    __syncthreads();

    // ---- flush block partials to global accumulators
    float* sg = s_g + (size_t)b * LBL * CH;
    #pragma unroll
    for (int i = 0; i < 8; ++i) {
        const int idx = tid + i * TPB;          // 0..2047
        const int l = idx >> 5, c = idx & 31;
        unsafeAtomicAdd(&sg[idx], s_blk[l][c]);
    }
    if (tid < LBL) {
        float q = 0.f;
        #pragma unroll
        for (int c = 0; c < CH; ++c) q += ss_blk[tid][c];
        unsafeAtomicAdd(&q_g[b * LBL + tid], q);
        unsafeAtomicAdd(&c_g[b * LBL + tid], (float)c_hist[tid]);
    }
}

__global__ __launch_bounds__(1024) void finalize(
    const float* __restrict__ s_g, const float* __restrict__ q_g,
    const float* __restrict__ c_g, float* __restrict__ out)
{
    const int t = threadIdx.x;        // 0..1023
    const int b = t >> 6;             // one wave per batch
    const int l = t & 63;

    const float cnt = c_g[b * LBL + l];
    const float q   = q_g[b * LBL + l];
    const float* sg = s_g + ((size_t)b * LBL + l) * CH;
    float sum2 = 0.f;
    #pragma unroll
    for (int c = 0; c < CH; ++c) sum2 = fmaf(sg[c], sg[c], sum2);

    float var_sum = 0.f;
    if (cnt > 1.f) var_sum = (q - sum2 / cnt) / (cnt - 1.f);

    float v       = (l != 0) ? var_sum : 0.f;
    float present = (l != 0 && cnt > 0.f) ? 1.f : 0.f;

    #pragma unroll
    for (int off = 32; off > 0; off >>= 1) {
        v       += __shfl_down(v, off);
        present += __shfl_down(present, off);
    }

    __shared__ float partial[BATCH];
    if (l == 0) partial[b] = v / (present + 1e-8f);
    __syncthreads();
    if (t == 0) {
        float acc = 0.f;
        #pragma unroll
        for (int i = 0; i < BATCH; ++i) acc += partial[i];
        out[0] = acc / (float)BATCH;
    }
}

// Fallback if ws is too small: one block per batch, LDS atomics (slow, correct).
__global__ __launch_bounds__(1024) void fallback_all(
    const float* __restrict__ x, const int* __restrict__ tg,
    float* __restrict__ out)
{
    __shared__ float s_l[CH][LBL];
    __shared__ float q_l[LBL];
    __shared__ float c_l[LBL];

    const int b   = blockIdx.x;
    const int tid = threadIdx.x;

    for (int i = tid; i < CH * LBL; i += 1024) (&s_l[0][0])[i] = 0.f;
    if (tid < LBL) { q_l[tid] = 0.f; c_l[tid] = 0.f; }
    __syncthreads();

    const float* xb = x  + (size_t)b * CH * PIX;
    const int*   tb = tg + (size_t)b * PIX;

    for (int base = 0; base < PIX; base += 1024 * 4) {
        const int p = base + tid * 4;
        const int4 lab = *reinterpret_cast<const int4*>(tb + p);
        float q0 = 0.f, q1 = 0.f, q2 = 0.f, q3 = 0.f;
        #pragma unroll 8
        for (int c = 0; c < CH; ++c) {
            const float4 v = *reinterpret_cast<const float4*>(xb + (size_t)c * PIX + p);
            unsafeAtomicAdd(&s_l[c][lab.x], v.x);
            unsafeAtomicAdd(&s_l[c][lab.y], v.y);
            unsafeAtomicAdd(&s_l[c][lab.z], v.z);
            unsafeAtomicAdd(&s_l[c][lab.w], v.w);
            q0 = fmaf(v.x, v.x, q0);
            q1 = fmaf(v.y, v.y, q1);
            q2 = fmaf(v.z, v.z, q2);
            q3 = fmaf(v.w, v.w, q3);
        }
        unsafeAtomicAdd(&q_l[lab.x], q0);
        unsafeAtomicAdd(&q_l[lab.y], q1);
        unsafeAtomicAdd(&q_l[lab.z], q2);
        unsafeAtomicAdd(&q_l[lab.w], q3);
        unsafeAtomicAdd(&c_l[lab.x], 1.f);
        unsafeAtomicAdd(&c_l[lab.y], 1.f);
        unsafeAtomicAdd(&c_l[lab.z], 1.f);
        unsafeAtomicAdd(&c_l[lab.w], 1.f);
    }
    __syncthreads();

    if (tid < LBL) {
        const int l = tid;
        const float cnt = c_l[l];
        const float q   = q_l[l];
        float sum2 = 0.f;
        #pragma unroll
        for (int c = 0; c < CH; ++c) sum2 = fmaf(s_l[c][l], s_l[c][l], sum2);
        float var_sum = 0.f;
        if (cnt > 1.f) var_sum = (q - sum2 / cnt) / (cnt - 1.f);
        float v       = (l != 0) ? var_sum : 0.f;
        float present = (l != 0 && cnt > 0.f) ? 1.f : 0.f;
        #pragma unroll
        for (int off = 32; off > 0; off >>= 1) {
            v       += __shfl_down(v, off);
            present += __shfl_down(present, off);
        }
        if (l == 0)
            unsafeAtomicAdd(out, v / (present + 1e-8f) / (float)BATCH);
    }
}

extern "C" void kernel_launch(void* const* d_in, const int* in_sizes, int n_in,
                              void* d_out, int out_size, void* d_ws, size_t ws_size,
                              hipStream_t stream)
{
    const float* x  = (const float*)d_in[0];
    const int*   tg = (const int*)d_in[1];
    float* out = (float*)d_out;
    float* ws  = (float*)d_ws;

    if (ws_size >= WS_FLOATS * sizeof(float)) {
        hipMemsetAsync(d_ws, 0, WS_FLOATS * sizeof(float), stream);
        dim3 grid(BPB, BATCH);
        seg_mfma<<<grid, TPB, 0, stream>>>(x, tg, ws, ws + Q_OFF, ws + C_OFF);
        finalize<<<1, 1024, 0, stream>>>(ws, ws + Q_OFF, ws + C_OFF, out);
    } else {
        hipMemsetAsync(d_out, 0, sizeof(float), stream);
        fallback_all<<<BATCH, 1024, 0, stream>>>(x, tg, out);
    }
}